// Round 16
// baseline (147.586 us; speedup 1.0000x reference)
//
#include <hip/hip_runtime.h>
#include <hip/hip_bf16.h>
#include <stdint.h>
#include <stddef.h>

// MDCT as folded GEMM. out[512, 32784] = D[512,512] . V[512, 32784]
//   V[c][j] = j<256:  x[g+j] - x[g+511-j]
//             j>=256: x[g+j+256] + x[g+1279-j],   g = o*512 - 512 (per batch)
// Precision: single fp16 product; absmax 0.03125 vs threshold 0.1069.
//
// R15: 8-WAVE BLOCKS. All six prior gemm variants shared 256-thread blocks
// x 2 resident = 2 waves/SIMD — with barrier-locked phases a SIMD often has
// ZERO MFMA-ready waves (MfmaUtil pinned 13-15%). This round: 512 threads,
// same 128x128 tile, same verified 2-phase counted-vmcnt schedule, wave
// tile 32x64 (wr=wid>>1 m-slot, wc=wid&1 n-slot; acc[2][4]). 4 waves/SIMD.
// STAGE = 2 slots/thread -> ledger scales: prologue 4 outstanding, STEP
// stages +4, WAITV(4) drains current tile, iter7 WAITV(0). Epilogue keeps
// the verified col^((row&12)<<2) involution; read-back 16 rows/wave.
// Predict MfmaUtil -> 20-25%, gemm 40 -> 30-34us, total ~132-136.

constexpr int N_ = 512;
constexpr int T_ = 2048;
constexpr int B_ = 16;
constexpr int LEN = N_ * T_;              // 2^20 per batch
constexpr int FRAMES = T_ + 1;            // 2049
constexpr int COLS = B_ * FRAMES;         // 32784
constexpr int NT_TILES = 257;
constexpr int COLS_PAD = NT_TILES * 128;  // 32896
constexpr int KF = 512;
constexpr int BK = 64;
constexpr int TILE_H = 128 * BK;          // elements per LDS buffer (8192)

typedef __attribute__((ext_vector_type(8))) _Float16 f16x8;
typedef __attribute__((ext_vector_type(4))) _Float16 f16x4;
typedef __attribute__((ext_vector_type(4))) float f32x4;

#define GLD16(gptr, lptr)                                                     \
  __builtin_amdgcn_global_load_lds(                                           \
      (const __attribute__((address_space(1))) unsigned int*)(gptr),          \
      (__attribute__((address_space(3))) unsigned int*)(lptr), 16, 0, 0)

// ---------------- Kernel 1: gather filter -> fp16 D -------------------------
__global__ void prep_filter(const float* __restrict__ f,
                            _Float16* __restrict__ D) {
  int idx = (blockIdx.x * 256 + threadIdx.x) * 4;
  int k = idx >> 9;
  int j = idx & 511;
  int t = (j < 256) ? j : (j + 256);
  const float4 v = *(const float4*)&f[k * 1024 + t];
  f16x4 h = {(_Float16)v.x, (_Float16)v.y, (_Float16)v.z, (_Float16)v.w};
  *(f16x4*)&D[k * KF + j] = h;
}

// ---------------- Kernel 2: fold x -> V fp16, one wave per column -----------
__global__ void fold_x(const float* __restrict__ x, _Float16* __restrict__ V) {
  const int blk = (blockIdx.x & 7) * 1028 + (blockIdx.x >> 3);
  const int c = blk * 4 + (threadIdx.x >> 6);  // 4 columns per block
  const int l = threadIdx.x & 63;
  const bool mi = (l < 32);
  const int j0 = mi ? (l * 8) : (256 + (l - 32) * 8);
  const float sgn = mi ? -1.0f : 1.0f;
  float4 a0 = {0.f, 0.f, 0.f, 0.f}, a1 = {0.f, 0.f, 0.f, 0.f};
  float4 r0 = {0.f, 0.f, 0.f, 0.f}, r1 = {0.f, 0.f, 0.f, 0.f};
  if (c < COLS) {
    int b = (int)((unsigned)c / (unsigned)FRAMES);
    int o = c - b * FRAMES;
    const int lo = b * LEN;
    const int g = lo + o * N_ - N_;            // absolute window start
    const int fb = g + (mi ? j0 : (j0 + 256)); // fwd segment (8 floats)
    const int rb = g + (mi ? (504 - j0) : (1272 - j0)); // rev segment
    if ((unsigned)(fb - lo) <= (unsigned)(LEN - 8)) {
      a0 = *(const float4*)(x + fb);
      a1 = *(const float4*)(x + fb + 4);
    }
    if ((unsigned)(rb - lo) <= (unsigned)(LEN - 8)) {
      r0 = *(const float4*)(x + rb);
      r1 = *(const float4*)(x + rb + 4);
    }
  }
  f16x8 h;
  h[0] = (_Float16)__builtin_fmaf(sgn, r1.w, a0.x);
  h[1] = (_Float16)__builtin_fmaf(sgn, r1.z, a0.y);
  h[2] = (_Float16)__builtin_fmaf(sgn, r1.y, a0.z);
  h[3] = (_Float16)__builtin_fmaf(sgn, r1.x, a0.w);
  h[4] = (_Float16)__builtin_fmaf(sgn, r0.w, a1.x);
  h[5] = (_Float16)__builtin_fmaf(sgn, r0.z, a1.y);
  h[6] = (_Float16)__builtin_fmaf(sgn, r0.y, a1.z);
  h[7] = (_Float16)__builtin_fmaf(sgn, r0.x, a1.w);
  if (c < COLS_PAD) *(f16x8*)&V[(size_t)c * KF + j0] = h;
}

// ---------------- Kernel 3: C = D . V, fp16 MFMA ----------------------------
// 128x128 tile, BK=64 static dbuf, counted-vmcnt 2-phase, EIGHT waves
// (4x2 of 32x64), 16x16x32 f16. Grid: 1056; id -> xcd=id&7, s=id>>3,
// m=s&3, nt=(s>>2)*8+xcd. Epilogue: swizzled LDS-transpose (R8-verified).
__global__ __launch_bounds__(512, 4) void gemm_fold(
    const _Float16* __restrict__ D, const _Float16* __restrict__ V,
    float* __restrict__ out) {
  // One 64 KB block; k-loop uses 4 compile-time-disjoint 16 KB quarters.
  // Epilogue reuses the whole block as a swizzled 128x128 f32 tile.
  __shared__ __align__(16) _Float16 SMEM[4 * TILE_H];
  _Float16* const As0 = SMEM;
  _Float16* const Bs0 = SMEM + TILE_H;
  _Float16* const As1 = SMEM + 2 * TILE_H;
  _Float16* const Bs1 = SMEM + 3 * TILE_H;

  const int id = blockIdx.x;
  const int xcd = id & 7;
  const int sb = id >> 3;
  const int nt = (sb >> 2) * 8 + xcd;
  if (nt >= NT_TILES) return;
  const int m0 = (sb & 3) * 128;
  const int n0 = nt * 128;

  // De-convoy: anti-phase half the blocks.
  if ((id >> 8) & 1) {
    __builtin_amdgcn_s_sleep(15);
  }

  const int tid = threadIdx.x;
  const int wid = tid >> 6;          // 0..7
  const int lane = tid & 63;
  const int quad = lane >> 4;
  const int l16 = lane & 15;
  const int mw = (wid >> 1) * 32;    // wave m-slot: 4 slots of 32 rows
  const int nw = (wid & 1) * 64;     // wave n-slot: 2 slots of 64 cols

  f32x4 acc[2][4];
#pragma unroll
  for (int i = 0; i < 2; ++i)
#pragma unroll
    for (int j = 0; j < 4; ++j) acc[i][j] = (f32x4){0.f, 0.f, 0.f, 0.f};

#define STAGE(AS, BS, KT)                                                     \
  do {                                                                        \
    const int kb_ = (KT) * BK;                                                \
    _Pragma("unroll")                                                         \
    for (int it = 0; it < 2; ++it) {                                          \
      const int S_ = it * 512 + tid;   /* LDS slot = uniform base + lane */   \
      const int r_ = S_ >> 3;          /* tile row */                         \
      const int c_ = (S_ & 7) ^ (r_ & 7); /* swizzled global chunk */         \
      const int g_ = kb_ + c_ * 8;                                            \
      GLD16(D + (size_t)(m0 + r_) * KF + g_, &(AS)[S_ * 8]);                  \
      GLD16(V + (size_t)(n0 + r_) * KF + g_, &(BS)[S_ * 8]);                  \
    }                                                                         \
  } while (0)

#define COMPUTE(AS, BS)                                                       \
  do {                                                                        \
    _Pragma("unroll")                                                         \
    for (int ko = 0; ko < 2; ++ko) {                                          \
      f16x8 af[2], bf[4];                                                     \
      const int ca_ = ko * 4 + quad;                                          \
      _Pragma("unroll")                                                       \
      for (int i = 0; i < 2; ++i) {                                           \
        int ra_ = mw + i * 16 + l16;                                          \
        af[i] = *(const f16x8*)&(AS)[(ra_ * 8 + (ca_ ^ (ra_ & 7))) * 8];      \
      }                                                                       \
      _Pragma("unroll")                                                       \
      for (int j = 0; j < 4; ++j) {                                           \
        int rb_ = nw + j * 16 + l16;                                          \
        bf[j] = *(const f16x8*)&(BS)[(rb_ * 8 + (ca_ ^ (rb_ & 7))) * 8];      \
      }                                                                       \
      _Pragma("unroll")                                                       \
      for (int i = 0; i < 2; ++i)                                             \
        _Pragma("unroll")                                                     \
        for (int j = 0; j < 4; ++j)                                           \
          acc[i][j] = __builtin_amdgcn_mfma_f32_16x16x32_f16(af[i], bf[j],    \
                                                             acc[i][j],      \
                                                             0, 0, 0);        \
    }                                                                         \
  } while (0)

#define WAITV(N) asm volatile("s_waitcnt vmcnt(" #N ")" ::: "memory")
#define BAR() __builtin_amdgcn_s_barrier()
#define SCHED0() __builtin_amdgcn_sched_barrier(0)

  // Prologue: fill buffer 0 (tile 0). 4 VMEM in flight per thread.
  STAGE(As0, Bs0, 0);

  // WAITV(4): drain the oldest 4 (tile KT, aged one full iteration); the
  // 4 newest (tile KT+1) stay in flight across both barriers.
#define STEP(AScur, BScur, ASnxt, BSnxt, KT)                                  \
  do {                                                                        \
    if ((KT) < 7) {                                                           \
      STAGE(ASnxt, BSnxt, (KT) + 1);                                          \
      WAITV(4);                                                               \
    } else {                                                                  \
      WAITV(0);                                                               \
    }                                                                         \
    BAR();     /* collective: tile KT fully in LDS */                         \
    SCHED0();                                                                 \
    COMPUTE(AScur, BScur);                                                    \
    SCHED0();                                                                 \
    BAR();     /* all waves done reading -> buffer reusable */                \
  } while (0)

  STEP(As0, Bs0, As1, Bs1, 0);
  STEP(As1, Bs1, As0, Bs0, 1);
  STEP(As0, Bs0, As1, Bs1, 2);
  STEP(As1, Bs1, As0, Bs0, 3);
  STEP(As0, Bs0, As1, Bs1, 4);
  STEP(As1, Bs1, As0, Bs0, 5);
  STEP(As0, Bs0, As1, Bs1, 6);
  STEP(As1, Bs1, As0, Bs0, 7);

#undef STEP
#undef STAGE
#undef COMPUTE
#undef WAITV
#undef BAR
#undef SCHED0

  // ---------------- Epilogue ----------------
  // acc[i][j][r] holds C[m0 + mw + i*16 + quad*4 + r][n0 + nw + j*16 + l16].
  const int bs = n0 / FRAMES;
  const int os = n0 - bs * FRAMES;
  const bool fast = (os + 128 <= FRAMES) && (n0 + 128 <= COLS);

  if (fast) {
    // Swizzled dump (verified involution): element (row,col) stored at
    // col^sw, sw=(row&12)<<2; read Ct[row*128+(lane^sw)] = (row,lane).
    float* Ct = (float*)SMEM;
#pragma unroll
    for (int i = 0; i < 2; ++i) {
#pragma unroll
      for (int j = 0; j < 4; ++j) {
        const int Lr0 = mw + i * 16 + quad * 4;
        const int Lc = nw + j * 16 + l16;
#pragma unroll
        for (int r = 0; r < 4; ++r) {
          const int row = Lr0 + r;
          Ct[row * 128 + (Lc ^ ((row & 12) << 2))] = acc[i][j][r];
        }
      }
    }
    __syncthreads();
    float* const obase = out + (size_t)bs * N_ * FRAMES + os;
#pragma unroll 4
    for (int it2 = 0; it2 < 16; ++it2) {
      const int row = wid * 16 + it2;     // local row 0..127 (16 rows/wave)
      const int sw = (row & 12) << 2;
      const int grow = m0 + row;          // global row < 512
      const float v0 = Ct[row * 128 + (lane ^ sw)];          // C[grow][os+lane]
      const float v1 = Ct[row * 128 + ((64 + lane) ^ sw)];   // C[grow][os+64+lane]
      float* rp = obase + (size_t)grow * FRAMES;
      rp[lane] = v0;
      rp[64 + lane] = v1;
    }
  } else {
    // Straddle/tail blocks: verified scalar path.
#pragma unroll
    for (int i = 0; i < 2; ++i) {
#pragma unroll
      for (int j = 0; j < 4; ++j) {
        int col = n0 + nw + j * 16 + l16;
        if (col < COLS) {
          int b = col / FRAMES;
          int o = col - b * FRAMES;
          int rowb = m0 + mw + i * 16 + quad * 4;
          float* op = out + (size_t)b * N_ * FRAMES + (size_t)rowb * FRAMES + o;
#pragma unroll
          for (int r = 0; r < 4; ++r) op[(size_t)r * FRAMES] = acc[i][j][r];
        }
      }
    }
  }
}

// ---------------- Fallback: direct fp32 conv (if ws too small) --------------
__global__ void naive_conv(const float* __restrict__ x, const float* __restrict__ f,
                           float* __restrict__ out) {
  int col = blockIdx.x;
  int k = threadIdx.x;
  __shared__ float win[1024];
  int b = col / FRAMES;
  int o = col - b * FRAMES;
  const float* xb = x + (size_t)b * LEN;
  int g = o * N_ - N_;
  for (int t = threadIdx.x; t < 1024; t += 512) {
    int i = g + t;
    win[t] = (i >= 0 && i < LEN) ? xb[i] : 0.0f;
  }
  __syncthreads();
  float s = 0.0f;
  const float* fk = f + (size_t)k * 1024;
  for (int t = 0; t < 1024; ++t) s += win[t] * fk[t];
  out[(size_t)b * N_ * FRAMES + (size_t)k * FRAMES + o] = s;
}

extern "C" void kernel_launch(void* const* d_in, const int* in_sizes, int n_in,
                              void* d_out, int out_size, void* d_ws, size_t ws_size,
                              hipStream_t stream) {
  const float* x = (const float*)d_in[0];
  const float* f = (const float*)d_in[1];
  float* out = (float*)d_out;

  const size_t elems_D = (size_t)512 * 512;
  const size_t elems_V = (size_t)COLS_PAD * KF;
  const size_t need = (elems_D + elems_V) * sizeof(_Float16);

  if (ws_size < need) {
    naive_conv<<<COLS, 512, 0, stream>>>(x, f, out);
    return;
  }

  _Float16* D = (_Float16*)d_ws;
  _Float16* V = D + elems_D;

  prep_filter<<<256, 256, 0, stream>>>(f, D);
  fold_x<<<COLS_PAD / 4, 256, 0, stream>>>(x, V);
  // Grid 1056 = 132*8: covers nt=0..256, m=0..3 (max id 1048); tail exits.
  gemm_fold<<<1056, 512, 0, stream>>>(D, V, out);
}